// Round 1
// baseline (19733.418 us; speedup 1.0000x reference)
//
#include <hip/hip_runtime.h>
#include <hip/hip_bf16.h>
#include <math.h>

// Problem constants (Decoder_88871463288984)
// H=8 M=1024 K=128 V=128 F=4096 L=6 B=4 Q=1024 T=1024
#define NL 6
#define NH 8
#define MD 1024
#define HD 128
#define FF 4096
#define NB 4
#define NQ 1024
#define NT 1024
#define ROWS (NB*NQ)   // 4096

// ---------------------------------------------------------------------------
// LayerNorm: one block per row of 1024 floats. 256 threads * float4.
// ---------------------------------------------------------------------------
__global__ __launch_bounds__(256) void ln_kernel(
    const float* __restrict__ x, float* __restrict__ y,
    const float* __restrict__ g, const float* __restrict__ b)
{
    __shared__ float sdata[8];
    int row = blockIdx.x;
    int tid = threadIdx.x;
    const float* xr = x + (size_t)row * MD;
    float4 v = ((const float4*)xr)[tid];
    float s = v.x + v.y + v.z + v.w;
    #pragma unroll
    for (int o = 32; o > 0; o >>= 1) s += __shfl_down(s, o, 64);
    if ((tid & 63) == 0) sdata[tid >> 6] = s;
    __syncthreads();
    if (tid == 0) sdata[4] = sdata[0] + sdata[1] + sdata[2] + sdata[3];
    __syncthreads();
    float mean = sdata[4] * (1.0f / MD);
    float4 d = make_float4(v.x - mean, v.y - mean, v.z - mean, v.w - mean);
    float sq = d.x*d.x + d.y*d.y + d.z*d.z + d.w*d.w;
    #pragma unroll
    for (int o = 32; o > 0; o >>= 1) sq += __shfl_down(sq, o, 64);
    __syncthreads();
    if ((tid & 63) == 0) sdata[tid >> 6] = sq;
    __syncthreads();
    if (tid == 0) sdata[4] = sdata[0] + sdata[1] + sdata[2] + sdata[3];
    __syncthreads();
    float var = sdata[4] * (1.0f / MD);
    float rstd = rsqrtf(var + 1e-5f);
    float4 g4 = ((const float4*)g)[tid];
    float4 b4 = ((const float4*)b)[tid];
    float4 o;
    o.x = d.x * rstd * g4.x + b4.x;
    o.y = d.y * rstd * g4.y + b4.y;
    o.z = d.z * rstd * g4.z + b4.z;
    o.w = d.w * rstd * g4.w + b4.w;
    ((float4*)(y + (size_t)row * MD))[tid] = o;
}

// ---------------------------------------------------------------------------
// fp32 tiled GEMM: C[row,col] = sum_k A[row,k]*B[k,col]  (+ epilogue)
// Tile 128x128x16, 256 threads, 8x8 per thread.
// flags: 1 = B is per-head (H, Kdim, 128) layout (wq/wk/wv style)
//        2 = add bias[col]
//        4 = ReLU
//        8 = add residual res[row*ldc+col]
// ---------------------------------------------------------------------------
#define GBM 128
#define GBN 128
#define GBK 16

__global__ __launch_bounds__(256) void gemm_kernel(
    const float* __restrict__ A, int lda,
    const float* __restrict__ B, int ldb,
    float* __restrict__ C, int ldc,
    int Kdim, int flags,
    const float* __restrict__ bias,
    const float* __restrict__ res)
{
    __shared__ float As[GBK][GBM + 4];
    __shared__ float Bs[GBK][GBN + 4];
    int tid  = threadIdx.x;
    int row0 = blockIdx.y * GBM;
    int col0 = blockIdx.x * GBN;

    const float* Bbase;
    int bcol0, ldb_l;
    if (flags & 1) {
        Bbase = B + (size_t)(col0 / 128) * (size_t)Kdim * 128;
        bcol0 = 0; ldb_l = 128;
    } else {
        Bbase = B; bcol0 = col0; ldb_l = ldb;
    }

    int tx = tid & 15, ty = tid >> 4;
    float acc[8][8];
    #pragma unroll
    for (int i = 0; i < 8; i++)
        #pragma unroll
        for (int j = 0; j < 8; j++) acc[i][j] = 0.0f;

    int a_r0 = tid >> 2;            // 0..63
    int a_c  = (tid & 3) * 4;       // 0,4,8,12
    int a_r1 = a_r0 + 64;
    int b_r0 = tid >> 5;            // 0..7
    int b_c  = (tid & 31) * 4;      // 0..124
    int b_r1 = b_r0 + 8;

    for (int kt = 0; kt < Kdim; kt += GBK) {
        float4 av0 = *(const float4*)(A + (size_t)(row0 + a_r0) * lda + kt + a_c);
        float4 av1 = *(const float4*)(A + (size_t)(row0 + a_r1) * lda + kt + a_c);
        float4 bv0 = *(const float4*)(Bbase + (size_t)(kt + b_r0) * ldb_l + bcol0 + b_c);
        float4 bv1 = *(const float4*)(Bbase + (size_t)(kt + b_r1) * ldb_l + bcol0 + b_c);
        As[a_c + 0][a_r0] = av0.x; As[a_c + 1][a_r0] = av0.y;
        As[a_c + 2][a_r0] = av0.z; As[a_c + 3][a_r0] = av0.w;
        As[a_c + 0][a_r1] = av1.x; As[a_c + 1][a_r1] = av1.y;
        As[a_c + 2][a_r1] = av1.z; As[a_c + 3][a_r1] = av1.w;
        *(float4*)(&Bs[b_r0][b_c]) = bv0;
        *(float4*)(&Bs[b_r1][b_c]) = bv1;
        __syncthreads();
        #pragma unroll
        for (int k = 0; k < GBK; k++) {
            float a8[8], b8[8];
            *(float4*)(&a8[0]) = *(const float4*)(&As[k][ty * 8]);
            *(float4*)(&a8[4]) = *(const float4*)(&As[k][ty * 8 + 4]);
            *(float4*)(&b8[0]) = *(const float4*)(&Bs[k][tx * 8]);
            *(float4*)(&b8[4]) = *(const float4*)(&Bs[k][tx * 8 + 4]);
            #pragma unroll
            for (int i = 0; i < 8; i++)
                #pragma unroll
                for (int j = 0; j < 8; j++)
                    acc[i][j] += a8[i] * b8[j];
        }
        __syncthreads();
    }

    #pragma unroll
    for (int i = 0; i < 8; i++) {
        int row = row0 + ty * 8 + i;
        #pragma unroll
        for (int j4 = 0; j4 < 2; j4++) {
            int col = col0 + tx * 8 + j4 * 4;
            float4 c4 = make_float4(acc[i][j4*4+0], acc[i][j4*4+1],
                                    acc[i][j4*4+2], acc[i][j4*4+3]);
            if (flags & 2) {
                c4.x += bias[col+0]; c4.y += bias[col+1];
                c4.z += bias[col+2]; c4.w += bias[col+3];
            }
            if (flags & 4) {
                c4.x = fmaxf(c4.x, 0.f); c4.y = fmaxf(c4.y, 0.f);
                c4.z = fmaxf(c4.z, 0.f); c4.w = fmaxf(c4.w, 0.f);
            }
            if (flags & 8) {
                float4 r4 = *(const float4*)(res + (size_t)row * ldc + col);
                c4.x += r4.x; c4.y += r4.y; c4.z += r4.z; c4.w += r4.w;
            }
            *(float4*)(C + (size_t)row * ldc + col) = c4;
        }
    }
}

// ---------------------------------------------------------------------------
// Fused flash-style attention. q/k/v layouts: (B*S, H*HD) row-major.
// One block = 32 q-rows of one (b,h). T chunks of 32, online softmax.
// causal=1 -> mask t>q and skip fully-masked chunks.
// ---------------------------------------------------------------------------
__global__ __launch_bounds__(256) void attn_kernel(
    const float* __restrict__ qb, const float* __restrict__ kb,
    const float* __restrict__ vb, float* __restrict__ pre,
    int Tlen, int causal)
{
    __shared__ float Qs[32][132];
    __shared__ float Ks[32][132];
    __shared__ float Vs[32][132];
    __shared__ float Ss[32][33];
    __shared__ float mS[32], lS[32], aS[32];

    int bh = blockIdx.y;
    int b = bh >> 3, h = bh & 7;
    int q0 = blockIdx.x * 32;
    int tid = threadIdx.x;
    const float scale = 0.08838834764831845f;   // 1/sqrt(128)

    // load Q tile (32 x 128)
    #pragma unroll
    for (int i = 0; i < 4; i++) {
        int idx = tid + i * 256;
        int r = idx >> 5, c4 = idx & 31;
        float4 v = *(const float4*)(qb + (size_t)(b * NQ + q0 + r) * MD + h * HD + c4 * 4);
        *(float4*)(&Qs[r][c4 * 4]) = v;
    }
    float O[16];
    #pragma unroll
    for (int i = 0; i < 16; i++) O[i] = 0.0f;
    if (tid < 32) { mS[tid] = -INFINITY; lS[tid] = 0.0f; }
    __syncthreads();

    int ro = tid & 31;            // O row
    int cb = (tid >> 5) * 16;     // O col base
    int sr = tid >> 3;            // S row
    int sj = (tid & 7) * 4;       // S col base

    int nchunks = causal ? (blockIdx.x + 1) : (Tlen / 32);
    for (int tc = 0; tc < nchunks; tc++) {
        int t0 = tc * 32;
        #pragma unroll
        for (int i = 0; i < 4; i++) {
            int idx = tid + i * 256;
            int r = idx >> 5, c4 = idx & 31;
            size_t off = (size_t)(b * NT + t0 + r) * MD + h * HD + c4 * 4;
            *(float4*)(&Ks[r][c4 * 4]) = *(const float4*)(kb + off);
            *(float4*)(&Vs[r][c4 * 4]) = *(const float4*)(vb + off);
        }
        __syncthreads();

        // S[sr][sj..sj+3] = Q[sr,:] . K[sj+i,:]
        float s0 = 0, s1 = 0, s2 = 0, s3 = 0;
        for (int d = 0; d < 128; d += 4) {
            float4 qv = *(const float4*)(&Qs[sr][d]);
            float4 k0 = *(const float4*)(&Ks[sj + 0][d]);
            float4 k1 = *(const float4*)(&Ks[sj + 1][d]);
            float4 k2 = *(const float4*)(&Ks[sj + 2][d]);
            float4 k3 = *(const float4*)(&Ks[sj + 3][d]);
            s0 += qv.x*k0.x + qv.y*k0.y + qv.z*k0.z + qv.w*k0.w;
            s1 += qv.x*k1.x + qv.y*k1.y + qv.z*k1.z + qv.w*k1.w;
            s2 += qv.x*k2.x + qv.y*k2.y + qv.z*k2.z + qv.w*k2.w;
            s3 += qv.x*k3.x + qv.y*k3.y + qv.z*k3.z + qv.w*k3.w;
        }
        int gq = q0 + sr;
        s0 *= scale; s1 *= scale; s2 *= scale; s3 *= scale;
        if (causal) {
            if (t0 + sj + 0 > gq) s0 = -1e30f;
            if (t0 + sj + 1 > gq) s1 = -1e30f;
            if (t0 + sj + 2 > gq) s2 = -1e30f;
            if (t0 + sj + 3 > gq) s3 = -1e30f;
        }
        Ss[sr][sj + 0] = s0; Ss[sr][sj + 1] = s1;
        Ss[sr][sj + 2] = s2; Ss[sr][sj + 3] = s3;
        __syncthreads();

        // per-row online softmax stats (32 threads)
        if (tid < 32) {
            int r = tid;
            float mold = mS[r];
            float mc = mold;
            #pragma unroll 8
            for (int j = 0; j < 32; j++) mc = fmaxf(mc, Ss[r][j]);
            float alpha = __expf(mold - mc);
            float psum = 0.0f;
            #pragma unroll 8
            for (int j = 0; j < 32; j++) {
                float p = __expf(Ss[r][j] - mc);
                Ss[r][j] = p; psum += p;
            }
            mS[r] = mc;
            lS[r] = lS[r] * alpha + psum;
            aS[r] = alpha;
        }
        __syncthreads();

        // O rescale + P*V
        float alpha = aS[ro];
        #pragma unroll
        for (int i = 0; i < 16; i++) O[i] *= alpha;
        for (int j = 0; j < 32; j++) {
            float p = Ss[ro][j];
            #pragma unroll
            for (int c4 = 0; c4 < 4; c4++) {
                float4 v4 = *(const float4*)(&Vs[j][cb + c4 * 4]);
                O[c4*4+0] += p * v4.x; O[c4*4+1] += p * v4.y;
                O[c4*4+2] += p * v4.z; O[c4*4+3] += p * v4.w;
            }
        }
        __syncthreads();
    }

    float linv = 1.0f / lS[ro];
    #pragma unroll
    for (int c4 = 0; c4 < 4; c4++) {
        float4 o4 = make_float4(O[c4*4+0]*linv, O[c4*4+1]*linv,
                                O[c4*4+2]*linv, O[c4*4+3]*linv);
        *(float4*)(pre + (size_t)(b * NQ + q0 + ro) * MD + h * HD + cb + c4 * 4) = o4;
    }
}

// ---------------------------------------------------------------------------
extern "C" void kernel_launch(void* const* d_in, const int* in_sizes, int n_in,
                              void* d_out, int out_size, void* d_ws, size_t ws_size,
                              hipStream_t stream)
{
    const float* enc  = (const float*)d_in[0];
    const float* x    = (const float*)d_in[1];
    // d_in[2..4]: position_mask (==0), qt_self_mask (==causal), qt_cross_mask (==0)
    const float* swq  = (const float*)d_in[5];
    const float* swk  = (const float*)d_in[6];
    const float* swv  = (const float*)d_in[7];
    const float* swo  = (const float*)d_in[8];
    const float* cwq  = (const float*)d_in[9];
    const float* cwk  = (const float*)d_in[10];
    const float* cwv  = (const float*)d_in[11];
    const float* cwo  = (const float*)d_in[12];
    const float* w1   = (const float*)d_in[13];
    const float* b1   = (const float*)d_in[14];
    const float* w2   = (const float*)d_in[15];
    const float* b2   = (const float*)d_in[16];
    const float* ln1g = (const float*)d_in[17];
    const float* ln1b = (const float*)d_in[18];
    const float* ln2g = (const float*)d_in[19];
    const float* ln2b = (const float*)d_in[20];
    const float* ln3g = (const float*)d_in[21];
    const float* ln3b = (const float*)d_in[22];

    float* h  = (float*)d_out;           // hidden state lives in d_out
    float* ws = (float*)d_ws;
    const size_t T16 = (size_t)ROWS * MD;      // 4M floats
    float* nb = ws;
    float* qb = nb + T16;
    float* kb = qb + T16;
    float* vb = kb + T16;
    float* pr = vb + T16;
    float* sb = pr + T16;                       // ROWS x FF (16M floats)

    hipMemcpyAsync(h, x, T16 * sizeof(float), hipMemcpyDeviceToDevice, stream);

    dim3 blk(256);
    dim3 gProj(MD / GBN, ROWS / GBM);     // (8, 32)
    dim3 gFfn1(FF / GBN, ROWS / GBM);     // (32, 32)
    dim3 gAttn(NQ / 32, NB * NH);         // (32, 32)

    const size_t WOF = (size_t)NH * MD * HD;    // per-layer attn weight stride (1M)
    const size_t W1S = (size_t)MD * FF;         // 4M

    for (int l = 0; l < NL; l++) {
        // ---- self attention ----
        ln_kernel<<<ROWS, blk, 0, stream>>>(h, nb, ln1g + l * MD, ln1b + l * MD);
        gemm_kernel<<<gProj, blk, 0, stream>>>(nb, MD, swq + l * WOF, 0, qb, MD, MD, 1, nullptr, nullptr);
        gemm_kernel<<<gProj, blk, 0, stream>>>(nb, MD, swk + l * WOF, 0, kb, MD, MD, 1, nullptr, nullptr);
        gemm_kernel<<<gProj, blk, 0, stream>>>(nb, MD, swv + l * WOF, 0, vb, MD, MD, 1, nullptr, nullptr);
        attn_kernel<<<gAttn, blk, 0, stream>>>(qb, kb, vb, pr, NT, 1);
        gemm_kernel<<<gProj, blk, 0, stream>>>(pr, MD, swo + l * WOF, MD, h, MD, MD, 8, nullptr, h);

        // ---- cross attention ----
        ln_kernel<<<ROWS, blk, 0, stream>>>(h, nb, ln2g + l * MD, ln2b + l * MD);
        gemm_kernel<<<gProj, blk, 0, stream>>>(nb, MD, cwq + l * WOF, 0, qb, MD, MD, 1, nullptr, nullptr);
        gemm_kernel<<<gProj, blk, 0, stream>>>(enc, MD, cwk + l * WOF, 0, kb, MD, MD, 1, nullptr, nullptr);
        gemm_kernel<<<gProj, blk, 0, stream>>>(enc, MD, cwv + l * WOF, 0, vb, MD, MD, 1, nullptr, nullptr);
        attn_kernel<<<gAttn, blk, 0, stream>>>(qb, kb, vb, pr, NT, 0);
        gemm_kernel<<<gProj, blk, 0, stream>>>(pr, MD, cwo + l * WOF, MD, h, MD, MD, 8, nullptr, h);

        // ---- FFN ----
        ln_kernel<<<ROWS, blk, 0, stream>>>(h, nb, ln3g + l * MD, ln3b + l * MD);
        gemm_kernel<<<gFfn1, blk, 0, stream>>>(nb, MD, w1 + l * W1S, FF, sb, FF, MD, 2 | 4, b1 + l * FF, nullptr);
        gemm_kernel<<<gProj, blk, 0, stream>>>(sb, FF, w2 + l * W1S, MD, h, MD, FF, 2 | 8, b2 + l * MD, h);
    }
}

// Round 2
// 4281.177 us; speedup vs baseline: 4.6093x; 4.6093x over previous
//
#include <hip/hip_runtime.h>
#include <math.h>

// Problem constants (Decoder_88871463288984)
#define NL 6
#define NH 8
#define MD 1024
#define HD 128
#define FF 4096
#define NB 4
#define NQ 1024
#define NT 1024
#define ROWS (NB*NQ)   // 4096

typedef __attribute__((ext_vector_type(8))) short bf16x8;
typedef __attribute__((ext_vector_type(4))) float f32x4;

// fp32 -> bf16, round-to-nearest-even
__device__ __forceinline__ unsigned short f2bf(float f) {
    unsigned int u = __float_as_uint(f);
    u += 0x7fffu + ((u >> 16) & 1u);
    return (unsigned short)(u >> 16);
}

// async global->LDS, 16 bytes per lane (dst must be wave-uniform base + lane*16)
__device__ __forceinline__ void load16_lds(const unsigned short* g, unsigned short* l) {
    __builtin_amdgcn_global_load_lds(
        (const __attribute__((address_space(1))) unsigned int*)g,
        (__attribute__((address_space(3))) unsigned int*)l, 16, 0, 0);
}

// ---------------------------------------------------------------------------
// LayerNorm: fp32 in (h), bf16 out. One block per row of 1024.
// ---------------------------------------------------------------------------
__global__ __launch_bounds__(256) void ln_kernel(
    const float* __restrict__ x, unsigned short* __restrict__ y,
    const float* __restrict__ g, const float* __restrict__ b)
{
    __shared__ float sdata[8];
    int row = blockIdx.x;
    int tid = threadIdx.x;
    const float* xr = x + (size_t)row * MD;
    float4 v = ((const float4*)xr)[tid];
    float s = v.x + v.y + v.z + v.w;
    #pragma unroll
    for (int o = 32; o > 0; o >>= 1) s += __shfl_down(s, o, 64);
    if ((tid & 63) == 0) sdata[tid >> 6] = s;
    __syncthreads();
    if (tid == 0) sdata[4] = sdata[0] + sdata[1] + sdata[2] + sdata[3];
    __syncthreads();
    float mean = sdata[4] * (1.0f / MD);
    float4 d = make_float4(v.x - mean, v.y - mean, v.z - mean, v.w - mean);
    float sq = d.x*d.x + d.y*d.y + d.z*d.z + d.w*d.w;
    #pragma unroll
    for (int o = 32; o > 0; o >>= 1) sq += __shfl_down(sq, o, 64);
    __syncthreads();
    if ((tid & 63) == 0) sdata[tid >> 6] = sq;
    __syncthreads();
    if (tid == 0) sdata[4] = sdata[0] + sdata[1] + sdata[2] + sdata[3];
    __syncthreads();
    float var = sdata[4] * (1.0f / MD);
    float rstd = rsqrtf(var + 1e-5f);
    float4 g4 = ((const float4*)g)[tid];
    float4 b4 = ((const float4*)b)[tid];
    ushort4 o;
    o.x = f2bf(d.x * rstd * g4.x + b4.x);
    o.y = f2bf(d.y * rstd * g4.y + b4.y);
    o.z = f2bf(d.z * rstd * g4.z + b4.z);
    o.w = f2bf(d.w * rstd * g4.w + b4.w);
    *(ushort4*)(y + (size_t)row * MD + tid * 4) = o;
}

// ---------------------------------------------------------------------------
// fp32 -> bf16 cast (enc_out). n = grid*256*4 elements exactly.
// ---------------------------------------------------------------------------
__global__ __launch_bounds__(256) void cast_bf16(
    const float* __restrict__ x, unsigned short* __restrict__ y)
{
    int i = blockIdx.x * 256 + threadIdx.x;
    float4 v = ((const float4*)x)[i];
    ushort4 o;
    o.x = f2bf(v.x); o.y = f2bf(v.y); o.z = f2bf(v.z); o.w = f2bf(v.w);
    ((ushort4*)y)[i] = o;
}

// ---------------------------------------------------------------------------
// Batched transpose + cast: X fp32 (batch,R,C) -> Y bf16 (batch,C,R).
// 32x32 tiles, R,C multiples of 32. Grid: (C/32, R/32, batch).
// ---------------------------------------------------------------------------
__global__ __launch_bounds__(256) void transpose_cast(
    const float* __restrict__ X, unsigned short* __restrict__ Y, int R, int C)
{
    __shared__ float tile[32][33];
    int bz = blockIdx.z;
    int r0 = blockIdx.y * 32, c0 = blockIdx.x * 32;
    const float* Xb = X + (size_t)bz * R * C;
    unsigned short* Yb = Y + (size_t)bz * R * C;
    int tx = threadIdx.x & 31, ty = threadIdx.x >> 5;
    #pragma unroll
    for (int i = 0; i < 4; i++)
        tile[ty + i*8][tx] = Xb[(size_t)(r0 + ty + i*8) * C + c0 + tx];
    __syncthreads();
    #pragma unroll
    for (int i = 0; i < 4; i++)
        Yb[(size_t)(c0 + ty + i*8) * R + r0 + tx] = f2bf(tile[tx][ty + i*8]);
}

// ---------------------------------------------------------------------------
// bf16 MFMA GEMM (m97 structure): C[M,N] = A[M,K] * B[K,N], B given as
// B^T (N,K) row-major. Tile 128x128, BK=64, 4 waves each owning a 64x64
// quadrant as 4x4 mfma_f32_16x16x32_bf16 tiles, fp32 accum.
// flags: 1 = write V^T layout (b,h,d,t) bf16   (v-projection)
//        2 = fp32 out with residual accumulate (C += acc)
//        4 = add bias[col]
//        8 = ReLU
// ---------------------------------------------------------------------------
#define BM 128
#define BN 128
#define BKK 64

__global__ __launch_bounds__(256) void gemm_bf16(
    const unsigned short* __restrict__ A, int lda,
    const unsigned short* __restrict__ BT, int ldb,
    void* __restrict__ Cout, int ldc, int Kdim, int flags,
    const float* __restrict__ bias)
{
    __shared__ unsigned short As[BM * BKK];
    __shared__ unsigned short Bs[BN * BKK];
    int tid = threadIdx.x;
    int lane = tid & 63;
    int wave = tid >> 6;
    int row0 = blockIdx.y * BM;
    int col0 = blockIdx.x * BN;
    int mr = (wave & 1) * 64;
    int nc = (wave >> 1) * 64;
    int lr = lane & 15;
    int quad = lane >> 4;

    f32x4 acc[4][4];
    #pragma unroll
    for (int i = 0; i < 4; i++)
        #pragma unroll
        for (int j = 0; j < 4; j++) acc[i][j] = (f32x4)0.0f;

    for (int kt = 0; kt < Kdim; kt += BKK) {
        #pragma unroll
        for (int it = 0; it < 4; it++) {
            int idx = it * 256 + tid;
            int r = idx >> 3, c = (idx & 7) * 8;
            load16_lds(A + (size_t)(row0 + r) * lda + kt + c, &As[idx * 8]);
        }
        #pragma unroll
        for (int it = 0; it < 4; it++) {
            int idx = it * 256 + tid;
            int r = idx >> 3, c = (idx & 7) * 8;
            load16_lds(BT + (size_t)(col0 + r) * ldb + kt + c, &Bs[idx * 8]);
        }
        __syncthreads();
        #pragma unroll
        for (int ks = 0; ks < 2; ks++) {
            bf16x8 af[4], bfr[4];
            #pragma unroll
            for (int i = 0; i < 4; i++)
                af[i] = *(const bf16x8*)&As[(mr + i*16 + lr) * BKK + ks*32 + quad*8];
            #pragma unroll
            for (int j = 0; j < 4; j++)
                bfr[j] = *(const bf16x8*)&Bs[(nc + j*16 + lr) * BKK + ks*32 + quad*8];
            #pragma unroll
            for (int i = 0; i < 4; i++)
                #pragma unroll
                for (int j = 0; j < 4; j++)
                    acc[i][j] = __builtin_amdgcn_mfma_f32_16x16x32_bf16(
                        af[i], bfr[j], acc[i][j], 0, 0, 0);
        }
        __syncthreads();
    }

    float bvj[4];
    if (flags & 4) {
        #pragma unroll
        for (int j = 0; j < 4; j++) bvj[j] = bias[col0 + nc + j*16 + lr];
    } else {
        #pragma unroll
        for (int j = 0; j < 4; j++) bvj[j] = 0.0f;
    }

    if (flags & 1) {
        // V^T store: vbt[((b*8+h)*128 + d) * NT + t], 4 consecutive t packed
        unsigned short* V = (unsigned short*)Cout;
        #pragma unroll
        for (int i = 0; i < 4; i++) {
            int grow0 = row0 + mr + i*16 + quad*4;
            int bb = grow0 >> 10, tt = grow0 & 1023;
            #pragma unroll
            for (int j = 0; j < 4; j++) {
                int gcol = col0 + nc + j*16 + lr;
                int hh = gcol >> 7, dd = gcol & 127;
                ushort4 pk;
                pk.x = f2bf(acc[i][j][0]); pk.y = f2bf(acc[i][j][1]);
                pk.z = f2bf(acc[i][j][2]); pk.w = f2bf(acc[i][j][3]);
                *(ushort4*)(V + (((size_t)(bb*NH + hh)*HD + dd) * NT + tt)) = pk;
            }
        }
    } else if (flags & 2) {
        float* Cf = (float*)Cout;
        #pragma unroll
        for (int i = 0; i < 4; i++) {
            int grow0 = row0 + mr + i*16 + quad*4;
            #pragma unroll
            for (int j = 0; j < 4; j++) {
                int gcol = col0 + nc + j*16 + lr;
                #pragma unroll
                for (int r = 0; r < 4; r++) {
                    float v = acc[i][j][r] + bvj[j];
                    size_t off = (size_t)(grow0 + r) * ldc + gcol;
                    Cf[off] += v;
                }
            }
        }
    } else {
        unsigned short* Cb = (unsigned short*)Cout;
        #pragma unroll
        for (int i = 0; i < 4; i++) {
            int grow0 = row0 + mr + i*16 + quad*4;
            #pragma unroll
            for (int j = 0; j < 4; j++) {
                int gcol = col0 + nc + j*16 + lr;
                #pragma unroll
                for (int r = 0; r < 4; r++) {
                    float v = acc[i][j][r] + bvj[j];
                    if (flags & 8) v = fmaxf(v, 0.0f);
                    Cb[(size_t)(grow0 + r) * ldc + gcol] = f2bf(v);
                }
            }
        }
    }
}

// ---------------------------------------------------------------------------
// MFMA flash attention. qb,kb bf16 (tokens, h*128+d); vbt bf16 (b,h,d,t);
// pr bf16 out (tokens, h*128+d). Block = 4 waves, Q-tile 64 (16 rows/wave),
// T-chunks of 32. Online softmax per 4 rows/quad, P via LDS (C->A layout).
// Grid: (NQ/64, NB*NH).
// ---------------------------------------------------------------------------
__global__ __launch_bounds__(256) void attn_mfma(
    const unsigned short* __restrict__ qb, const unsigned short* __restrict__ kb,
    const unsigned short* __restrict__ vbt, unsigned short* __restrict__ pr,
    int causal)
{
    __shared__ unsigned short Qs[64 * 136];
    __shared__ unsigned short Ks[32 * 136];
    __shared__ unsigned short Vs[128 * 40];
    __shared__ unsigned short Ps[4 * 16 * 40];

    int tid = threadIdx.x;
    int lane = tid & 63, wave = tid >> 6;
    int lr = lane & 15, quad = lane >> 4;
    int bh = blockIdx.y;
    int b = bh >> 3, h = bh & 7;
    int q0 = blockIdx.x * 64;
    const float scale = 0.08838834764831845f;  // 1/sqrt(128)

    // stage Q tile 64x128 (padded rows of 136)
    #pragma unroll
    for (int it = 0; it < 4; it++) {
        int idx = it * 256 + tid;
        int r = idx >> 4, c = (idx & 15) * 8;
        *(uint4*)&Qs[r * 136 + c] =
            *(const uint4*)(qb + (size_t)(b*NQ + q0 + r) * MD + h*HD + c);
    }
    __syncthreads();
    bf16x8 aq[4];
    #pragma unroll
    for (int dk = 0; dk < 4; dk++)
        aq[dk] = *(const bf16x8*)&Qs[(wave*16 + lr) * 136 + dk*32 + quad*8];

    f32x4 acc[8];
    #pragma unroll
    for (int n = 0; n < 8; n++) acc[n] = (f32x4)0.0f;
    float m_run[4], l_run[4];
    #pragma unroll
    for (int r = 0; r < 4; r++) { m_run[r] = -1e30f; l_run[r] = 0.0f; }

    unsigned short* Pw = &Ps[wave * 16 * 40];
    int nch = causal ? (2 * blockIdx.x + 2) : (NT / 32);

    for (int tc = 0; tc < nch; tc++) {
        int t0 = tc * 32;
        __syncthreads();  // previous chunk's LDS reads complete
        // stage K chunk 32x128 -> Ks[32][136]
        #pragma unroll
        for (int it = 0; it < 2; it++) {
            int idx = it * 256 + tid;
            int r = idx >> 4, c = (idx & 15) * 8;
            *(uint4*)&Ks[r * 136 + c] =
                *(const uint4*)(kb + (size_t)(b*NT + t0 + r) * MD + h*HD + c);
        }
        // stage V^T chunk 128x32 -> Vs[128][40]
        #pragma unroll
        for (int it = 0; it < 2; it++) {
            int idx = it * 256 + tid;
            int r = idx >> 2, c = (idx & 3) * 8;
            *(uint4*)&Vs[r * 40 + c] =
                *(const uint4*)(vbt + ((size_t)(b*NH + h)*HD + r) * NT + t0 + c);
        }
        __syncthreads();

        // S = Q K^T for two 16-col t-tiles
        f32x4 s0 = (f32x4)0.0f, s1 = (f32x4)0.0f;
        #pragma unroll
        for (int dk = 0; dk < 4; dk++) {
            bf16x8 bk0 = *(const bf16x8*)&Ks[(lr) * 136 + dk*32 + quad*8];
            bf16x8 bk1 = *(const bf16x8*)&Ks[(16 + lr) * 136 + dk*32 + quad*8];
            s0 = __builtin_amdgcn_mfma_f32_16x16x32_bf16(aq[dk], bk0, s0, 0, 0, 0);
            s1 = __builtin_amdgcn_mfma_f32_16x16x32_bf16(aq[dk], bk1, s1, 0, 0, 0);
        }
        int grow_base = q0 + wave*16 + quad*4;
        #pragma unroll
        for (int r = 0; r < 4; r++) {
            float v0 = s0[r] * scale, v1 = s1[r] * scale;
            if (causal) {
                if (t0 + lr > grow_base + r)      v0 = -1e30f;
                if (t0 + 16 + lr > grow_base + r) v1 = -1e30f;
            }
            s0[r] = v0; s1[r] = v1;
        }

        // online softmax per row (replicated across the quad's 16 lanes)
        #pragma unroll
        for (int r = 0; r < 4; r++) {
            float mx = fmaxf(s0[r], s1[r]);
            #pragma unroll
            for (int off = 1; off < 16; off <<= 1)
                mx = fmaxf(mx, __shfl_xor(mx, off));
            mx = fmaxf(mx, m_run[r]);
            float alpha = __expf(m_run[r] - mx);
            float p0 = __expf(s0[r] - mx);
            float p1 = __expf(s1[r] - mx);
            Pw[(quad*4 + r) * 40 + lr]      = f2bf(p0);
            Pw[(quad*4 + r) * 40 + 16 + lr] = f2bf(p1);
            float psum = p0 + p1;
            #pragma unroll
            for (int off = 1; off < 16; off <<= 1)
                psum += __shfl_xor(psum, off);
            l_run[r] = l_run[r] * alpha + psum;
            m_run[r] = mx;
            #pragma unroll
            for (int n = 0; n < 8; n++) acc[n][r] *= alpha;
        }

        // PV: A-frag from Pw (wave-local, in-wave DS ordering), B-frags from Vs
        bf16x8 ap = *(const bf16x8*)&Pw[lr * 40 + quad * 8];
        #pragma unroll
        for (int n = 0; n < 8; n++) {
            bf16x8 bv = *(const bf16x8*)&Vs[(n*16 + lr) * 40 + quad * 8];
            acc[n] = __builtin_amdgcn_mfma_f32_16x16x32_bf16(ap, bv, acc[n], 0, 0, 0);
        }
    }

    float linv[4];
    #pragma unroll
    for (int r = 0; r < 4; r++) linv[r] = 1.0f / l_run[r];
    #pragma unroll
    for (int n = 0; n < 8; n++) {
        int gcol = h*HD + n*16 + lr;
        #pragma unroll
        for (int r = 0; r < 4; r++) {
            int grow = q0 + wave*16 + quad*4 + r;
            pr[(size_t)(b*NQ + grow) * MD + gcol] = f2bf(acc[n][r] * linv[r]);
        }
    }
}

// ---------------------------------------------------------------------------
extern "C" void kernel_launch(void* const* d_in, const int* in_sizes, int n_in,
                              void* d_out, int out_size, void* d_ws, size_t ws_size,
                              hipStream_t stream)
{
    const float* enc  = (const float*)d_in[0];
    const float* x    = (const float*)d_in[1];
    const float* swq  = (const float*)d_in[5];
    const float* swk  = (const float*)d_in[6];
    const float* swv  = (const float*)d_in[7];
    const float* swo  = (const float*)d_in[8];
    const float* cwq  = (const float*)d_in[9];
    const float* cwk  = (const float*)d_in[10];
    const float* cwv  = (const float*)d_in[11];
    const float* cwo  = (const float*)d_in[12];
    const float* w1   = (const float*)d_in[13];
    const float* b1   = (const float*)d_in[14];
    const float* w2   = (const float*)d_in[15];
    const float* b2   = (const float*)d_in[16];
    const float* ln1g = (const float*)d_in[17];
    const float* ln1b = (const float*)d_in[18];
    const float* ln2g = (const float*)d_in[19];
    const float* ln2b = (const float*)d_in[20];
    const float* ln3g = (const float*)d_in[21];
    const float* ln3b = (const float*)d_in[22];

    float* h = (float*)d_out;
    unsigned short* u = (unsigned short*)d_ws;
    const size_t MW = 1024 * 1024;
    unsigned short* nb   = u;             // 4M ushort
    unsigned short* encb = u + 4*MW;      // 4M
    unsigned short* qb   = u + 8*MW;      // 4M
    unsigned short* kb   = u + 12*MW;     // 4M
    unsigned short* vbt  = u + 16*MW;     // 4M
    unsigned short* pr   = u + 20*MW;     // 4M
    unsigned short* sb   = qb;            // aliases qb..pr (16M), FFN-only
    unsigned short* wb   = u + 24*MW;

    // upfront conversion needs (24 + 96) M ushort = 240 MiB total
    bool upfront = ws_size >= (size_t)240 * MW;

    hipMemcpyAsync(h, x, 4*MW*sizeof(float), hipMemcpyDeviceToDevice, stream);

    dim3 tb(256);
    cast_bf16<<<4096, tb, 0, stream>>>(enc, encb);

    if (upfront) {
        transpose_cast<<<dim3(4,32,48),  tb, 0, stream>>>(swq, wb + 0*MW,  1024, 128);
        transpose_cast<<<dim3(4,32,48),  tb, 0, stream>>>(swk, wb + 6*MW,  1024, 128);
        transpose_cast<<<dim3(4,32,48),  tb, 0, stream>>>(swv, wb + 12*MW, 1024, 128);
        transpose_cast<<<dim3(32,32,6),  tb, 0, stream>>>(swo, wb + 18*MW, 1024, 1024);
        transpose_cast<<<dim3(4,32,48),  tb, 0, stream>>>(cwq, wb + 24*MW, 1024, 128);
        transpose_cast<<<dim3(4,32,48),  tb, 0, stream>>>(cwk, wb + 30*MW, 1024, 128);
        transpose_cast<<<dim3(4,32,48),  tb, 0, stream>>>(cwv, wb + 36*MW, 1024, 128);
        transpose_cast<<<dim3(32,32,6),  tb, 0, stream>>>(cwo, wb + 42*MW, 1024, 1024);
        transpose_cast<<<dim3(128,32,6), tb, 0, stream>>>(w1,  wb + 48*MW, 1024, 4096);
        transpose_cast<<<dim3(32,128,6), tb, 0, stream>>>(w2,  wb + 72*MW, 4096, 1024);
    }

    dim3 gP(8, 32), gF1(32, 32), gA(16, 32);

    for (int l = 0; l < NL; l++) {
        unsigned short *pwq, *pwk, *pwv, *pwo, *pcq, *pck, *pcv, *pco, *pw1, *pw2;
        if (upfront) {
            pwq = wb + 0*MW  + l*MW;  pwk = wb + 6*MW  + l*MW;
            pwv = wb + 12*MW + l*MW;  pwo = wb + 18*MW + l*MW;
            pcq = wb + 24*MW + l*MW;  pck = wb + 30*MW + l*MW;
            pcv = wb + 36*MW + l*MW;  pco = wb + 42*MW + l*MW;
            pw1 = wb + 48*MW + l*4*MW; pw2 = wb + 72*MW + l*4*MW;
        } else {
            pwq = wb;        pwk = wb + 1*MW; pwv = wb + 2*MW; pwo = wb + 3*MW;
            pcq = wb + 4*MW; pck = wb + 5*MW; pcv = wb + 6*MW; pco = wb + 7*MW;
            pw1 = wb + 8*MW; pw2 = wb + 12*MW;
            transpose_cast<<<dim3(4,32,8),   tb, 0, stream>>>(swq + l*MW,   pwq, 1024, 128);
            transpose_cast<<<dim3(4,32,8),   tb, 0, stream>>>(swk + l*MW,   pwk, 1024, 128);
            transpose_cast<<<dim3(4,32,8),   tb, 0, stream>>>(swv + l*MW,   pwv, 1024, 128);
            transpose_cast<<<dim3(32,32,1),  tb, 0, stream>>>(swo + l*MW,   pwo, 1024, 1024);
            transpose_cast<<<dim3(4,32,8),   tb, 0, stream>>>(cwq + l*MW,   pcq, 1024, 128);
            transpose_cast<<<dim3(4,32,8),   tb, 0, stream>>>(cwk + l*MW,   pck, 1024, 128);
            transpose_cast<<<dim3(4,32,8),   tb, 0, stream>>>(cwv + l*MW,   pcv, 1024, 128);
            transpose_cast<<<dim3(32,32,1),  tb, 0, stream>>>(cwo + l*MW,   pco, 1024, 1024);
            transpose_cast<<<dim3(128,32,1), tb, 0, stream>>>(w1 + l*4*MW,  pw1, 1024, 4096);
            transpose_cast<<<dim3(32,128,1), tb, 0, stream>>>(w2 + l*4*MW,  pw2, 4096, 1024);
        }

        // ---- self attention ----
        ln_kernel<<<ROWS, tb, 0, stream>>>(h, nb, ln1g + l*MD, ln1b + l*MD);
        gemm_bf16<<<gP, tb, 0, stream>>>(nb, MD, pwq, MD, qb,  MD, MD, 0, nullptr);
        gemm_bf16<<<gP, tb, 0, stream>>>(nb, MD, pwk, MD, kb,  MD, MD, 0, nullptr);
        gemm_bf16<<<gP, tb, 0, stream>>>(nb, MD, pwv, MD, vbt, MD, MD, 1, nullptr);
        attn_mfma<<<gA, tb, 0, stream>>>(qb, kb, vbt, pr, 1);
        gemm_bf16<<<gP, tb, 0, stream>>>(pr, MD, pwo, MD, h,   MD, MD, 2, nullptr);

        // ---- cross attention ----
        ln_kernel<<<ROWS, tb, 0, stream>>>(h, nb, ln2g + l*MD, ln2b + l*MD);
        gemm_bf16<<<gP, tb, 0, stream>>>(nb,   MD, pcq, MD, qb,  MD, MD, 0, nullptr);
        gemm_bf16<<<gP, tb, 0, stream>>>(encb, MD, pck, MD, kb,  MD, MD, 0, nullptr);
        gemm_bf16<<<gP, tb, 0, stream>>>(encb, MD, pcv, MD, vbt, MD, MD, 1, nullptr);
        attn_mfma<<<gA, tb, 0, stream>>>(qb, kb, vbt, pr, 0);
        gemm_bf16<<<gP, tb, 0, stream>>>(pr, MD, pco, MD, h,   MD, MD, 2, nullptr);

        // ---- FFN ----
        ln_kernel<<<ROWS, tb, 0, stream>>>(h, nb, ln3g + l*MD, ln3b + l*MD);
        gemm_bf16<<<gF1, tb, 0, stream>>>(nb, MD, pw1, MD, sb, FF, MD, 4 | 8, b1 + l*FF);
        gemm_bf16<<<gP,  tb, 0, stream>>>(sb, FF, pw2, FF, h,  MD, FF, 2 | 4, b2 + l*MD);
    }
}

// Round 3
// 3723.693 us; speedup vs baseline: 5.2994x; 1.1497x over previous
//
#include <hip/hip_runtime.h>
#include <math.h>

// Problem constants (Decoder_88871463288984)
#define NL 6
#define NH 8
#define MD 1024
#define HD 128
#define FF 4096
#define NB 4
#define NQ 1024
#define NT 1024
#define ROWS (NB*NQ)   // 4096

typedef __attribute__((ext_vector_type(8))) short bf16x8;
typedef __attribute__((ext_vector_type(4))) float f32x4;

// fp32 -> bf16, round-to-nearest-even
__device__ __forceinline__ unsigned short f2bf(float f) {
    unsigned int u = __float_as_uint(f);
    u += 0x7fffu + ((u >> 16) & 1u);
    return (unsigned short)(u >> 16);
}

// async global->LDS, 16 bytes per lane (dst must be wave-uniform base + lane*16)
__device__ __forceinline__ void load16_lds(const unsigned short* g, unsigned short* l) {
    __builtin_amdgcn_global_load_lds(
        (const __attribute__((address_space(1))) unsigned int*)g,
        (__attribute__((address_space(3))) unsigned int*)l, 16, 0, 0);
}

// ---------------------------------------------------------------------------
// LayerNorm: fp32 in (h), bf16 out. One block per row of 1024.
// ---------------------------------------------------------------------------
__global__ __launch_bounds__(256) void ln_kernel(
    const float* __restrict__ x, unsigned short* __restrict__ y,
    const float* __restrict__ g, const float* __restrict__ b)
{
    __shared__ float sdata[8];
    int row = blockIdx.x;
    int tid = threadIdx.x;
    const float* xr = x + (size_t)row * MD;
    float4 v = ((const float4*)xr)[tid];
    float s = v.x + v.y + v.z + v.w;
    #pragma unroll
    for (int o = 32; o > 0; o >>= 1) s += __shfl_down(s, o, 64);
    if ((tid & 63) == 0) sdata[tid >> 6] = s;
    __syncthreads();
    if (tid == 0) sdata[4] = sdata[0] + sdata[1] + sdata[2] + sdata[3];
    __syncthreads();
    float mean = sdata[4] * (1.0f / MD);
    float4 d = make_float4(v.x - mean, v.y - mean, v.z - mean, v.w - mean);
    float sq = d.x*d.x + d.y*d.y + d.z*d.z + d.w*d.w;
    #pragma unroll
    for (int o = 32; o > 0; o >>= 1) sq += __shfl_down(sq, o, 64);
    __syncthreads();
    if ((tid & 63) == 0) sdata[tid >> 6] = sq;
    __syncthreads();
    if (tid == 0) sdata[4] = sdata[0] + sdata[1] + sdata[2] + sdata[3];
    __syncthreads();
    float var = sdata[4] * (1.0f / MD);
    float rstd = rsqrtf(var + 1e-5f);
    float4 g4 = ((const float4*)g)[tid];
    float4 b4 = ((const float4*)b)[tid];
    ushort4 o;
    o.x = f2bf(d.x * rstd * g4.x + b4.x);
    o.y = f2bf(d.y * rstd * g4.y + b4.y);
    o.z = f2bf(d.z * rstd * g4.z + b4.z);
    o.w = f2bf(d.w * rstd * g4.w + b4.w);
    *(ushort4*)(y + (size_t)row * MD + tid * 4) = o;
}

// ---------------------------------------------------------------------------
// fp32 -> bf16 cast (enc_out). n = grid*256*4 elements exactly.
// ---------------------------------------------------------------------------
__global__ __launch_bounds__(256) void cast_bf16(
    const float* __restrict__ x, unsigned short* __restrict__ y)
{
    int i = blockIdx.x * 256 + threadIdx.x;
    float4 v = ((const float4*)x)[i];
    ushort4 o;
    o.x = f2bf(v.x); o.y = f2bf(v.y); o.z = f2bf(v.z); o.w = f2bf(v.w);
    ((ushort4*)y)[i] = o;
}

// ---------------------------------------------------------------------------
// Batched transpose + cast: X fp32 (batch,R,C) -> Y bf16 (batch,C,R).
// ---------------------------------------------------------------------------
__global__ __launch_bounds__(256) void transpose_cast(
    const float* __restrict__ X, unsigned short* __restrict__ Y, int R, int C)
{
    __shared__ float tile[32][33];
    int bz = blockIdx.z;
    int r0 = blockIdx.y * 32, c0 = blockIdx.x * 32;
    const float* Xb = X + (size_t)bz * R * C;
    unsigned short* Yb = Y + (size_t)bz * R * C;
    int tx = threadIdx.x & 31, ty = threadIdx.x >> 5;
    #pragma unroll
    for (int i = 0; i < 4; i++)
        tile[ty + i*8][tx] = Xb[(size_t)(r0 + ty + i*8) * C + c0 + tx];
    __syncthreads();
    #pragma unroll
    for (int i = 0; i < 4; i++)
        Yb[(size_t)(c0 + ty + i*8) * R + r0 + tx] = f2bf(tile[tx][ty + i*8]);
}

// ---------------------------------------------------------------------------
// Shared bf16 MFMA GEMM body. Tile 128x128, BK=64, 4 waves x (4x4) 16x16x32.
// flags: 1 = write V^T layout (b,h,d,t) bf16
//        2 = fp32 atomicAdd into Cout (residual / split-K accumulate)
//        4 = add bias[col]
//        8 = ReLU
// ---------------------------------------------------------------------------
#define BKK 64

__device__ __forceinline__ void gemm_body(
    unsigned short* As, unsigned short* Bs,
    const unsigned short* __restrict__ A, int lda,
    const unsigned short* __restrict__ BT, int ldb,
    void* __restrict__ Cout, int ldc, int Kdim, int flags,
    const float* __restrict__ bias, int row0, int col0)
{
    int tid = threadIdx.x;
    int lane = tid & 63;
    int wave = tid >> 6;
    int mr = (wave & 1) * 64;
    int nc = (wave >> 1) * 64;
    int lr = lane & 15;
    int quad = lane >> 4;

    f32x4 acc[4][4];
    #pragma unroll
    for (int i = 0; i < 4; i++)
        #pragma unroll
        for (int j = 0; j < 4; j++) acc[i][j] = (f32x4)0.0f;

    for (int kt = 0; kt < Kdim; kt += BKK) {
        #pragma unroll
        for (int it = 0; it < 4; it++) {
            int idx = it * 256 + tid;
            int r = idx >> 3, c = (idx & 7) * 8;
            load16_lds(A + (size_t)(row0 + r) * lda + kt + c, &As[idx * 8]);
        }
        #pragma unroll
        for (int it = 0; it < 4; it++) {
            int idx = it * 256 + tid;
            int r = idx >> 3, c = (idx & 7) * 8;
            load16_lds(BT + (size_t)(col0 + r) * ldb + kt + c, &Bs[idx * 8]);
        }
        __syncthreads();
        #pragma unroll
        for (int ks = 0; ks < 2; ks++) {
            bf16x8 af[4], bfr[4];
            #pragma unroll
            for (int i = 0; i < 4; i++)
                af[i] = *(const bf16x8*)&As[(mr + i*16 + lr) * BKK + ks*32 + quad*8];
            #pragma unroll
            for (int j = 0; j < 4; j++)
                bfr[j] = *(const bf16x8*)&Bs[(nc + j*16 + lr) * BKK + ks*32 + quad*8];
            #pragma unroll
            for (int i = 0; i < 4; i++)
                #pragma unroll
                for (int j = 0; j < 4; j++)
                    acc[i][j] = __builtin_amdgcn_mfma_f32_16x16x32_bf16(
                        af[i], bfr[j], acc[i][j], 0, 0, 0);
        }
        __syncthreads();
    }

    float bvj[4];
    if (flags & 4) {
        #pragma unroll
        for (int j = 0; j < 4; j++) bvj[j] = bias[col0 + nc + j*16 + lr];
    } else {
        #pragma unroll
        for (int j = 0; j < 4; j++) bvj[j] = 0.0f;
    }

    if (flags & 1) {
        // V^T store: vbt[((b*8+h)*128 + d) * NT + t], 4 consecutive t packed
        unsigned short* V = (unsigned short*)Cout;
        #pragma unroll
        for (int i = 0; i < 4; i++) {
            int grow0 = row0 + mr + i*16 + quad*4;
            int bb = grow0 >> 10, tt = grow0 & 1023;
            #pragma unroll
            for (int j = 0; j < 4; j++) {
                int gcol = col0 + nc + j*16 + lr;
                int hh = gcol >> 7, dd = gcol & 127;
                ushort4 pk;
                pk.x = f2bf(acc[i][j][0]); pk.y = f2bf(acc[i][j][1]);
                pk.z = f2bf(acc[i][j][2]); pk.w = f2bf(acc[i][j][3]);
                *(ushort4*)(V + (((size_t)(bb*NH + hh)*HD + dd) * NT + tt)) = pk;
            }
        }
    } else if (flags & 2) {
        float* Cf = (float*)Cout;
        #pragma unroll
        for (int i = 0; i < 4; i++) {
            int grow0 = row0 + mr + i*16 + quad*4;
            #pragma unroll
            for (int j = 0; j < 4; j++) {
                int gcol = col0 + nc + j*16 + lr;
                #pragma unroll
                for (int r = 0; r < 4; r++) {
                    float v = acc[i][j][r] + bvj[j];
                    atomicAdd(&Cf[(size_t)(grow0 + r) * ldc + gcol], v);
                }
            }
        }
    } else {
        unsigned short* Cb = (unsigned short*)Cout;
        #pragma unroll
        for (int i = 0; i < 4; i++) {
            int grow0 = row0 + mr + i*16 + quad*4;
            #pragma unroll
            for (int j = 0; j < 4; j++) {
                int gcol = col0 + nc + j*16 + lr;
                #pragma unroll
                for (int r = 0; r < 4; r++) {
                    float v = acc[i][j][r] + bvj[j];
                    if (flags & 8) v = fmaxf(v, 0.0f);
                    Cb[(size_t)(grow0 + r) * ldc + gcol] = f2bf(v);
                }
            }
        }
    }
}

// Generic GEMM with K-split over blockIdx.z (Kper = K per split).
__global__ __launch_bounds__(256) void gemm_bf16(
    const unsigned short* __restrict__ A, int lda,
    const unsigned short* __restrict__ BT, int ldb,
    void* __restrict__ Cout, int ldc, int Kper, int flags,
    const float* __restrict__ bias)
{
    __shared__ unsigned short As[128 * BKK];
    __shared__ unsigned short Bs[128 * BKK];
    int row0 = blockIdx.y * 128, col0 = blockIdx.x * 128;
    int kbase = blockIdx.z * Kper;
    if (blockIdx.z) flags &= ~4;      // bias only once
    gemm_body(As, Bs, A + kbase, lda, BT + kbase, ldb, Cout, ldc,
              Kper, flags, bias, row0, col0);
}

// Fused Q/K/V projection: blockIdx.x in [0,24): weight = x>>3, col = (x&7)*128.
// Q uses Aq, K/V use Akv. V output goes to V^T layout.
__global__ __launch_bounds__(256) void gemm_qkv(
    const unsigned short* __restrict__ Aq,
    const unsigned short* __restrict__ Akv,
    const unsigned short* __restrict__ BTq,
    const unsigned short* __restrict__ BTk,
    const unsigned short* __restrict__ BTv,
    unsigned short* __restrict__ qb,
    unsigned short* __restrict__ kb,
    unsigned short* __restrict__ vbt)
{
    __shared__ unsigned short As[128 * BKK];
    __shared__ unsigned short Bs[128 * BKK];
    int w = blockIdx.x >> 3;
    int col0 = (blockIdx.x & 7) * 128;
    int row0 = blockIdx.y * 128;
    const unsigned short* A  = (w == 0) ? Aq : Akv;
    const unsigned short* BT = (w == 0) ? BTq : (w == 1) ? BTk : BTv;
    void* C  = (w == 0) ? (void*)qb : (w == 1) ? (void*)kb : (void*)vbt;
    int flags = (w == 2) ? 1 : 0;
    gemm_body(As, Bs, A, MD, BT, MD, C, MD, MD, flags, nullptr, row0, col0);
}

// ---------------------------------------------------------------------------
// MFMA flash attention (unchanged from round 2).
// ---------------------------------------------------------------------------
__global__ __launch_bounds__(256) void attn_mfma(
    const unsigned short* __restrict__ qb, const unsigned short* __restrict__ kb,
    const unsigned short* __restrict__ vbt, unsigned short* __restrict__ pr,
    int causal)
{
    __shared__ unsigned short Qs[64 * 136];
    __shared__ unsigned short Ks[32 * 136];
    __shared__ unsigned short Vs[128 * 40];
    __shared__ unsigned short Ps[4 * 16 * 40];

    int tid = threadIdx.x;
    int lane = tid & 63, wave = tid >> 6;
    int lr = lane & 15, quad = lane >> 4;
    int bh = blockIdx.y;
    int b = bh >> 3, h = bh & 7;
    int q0 = blockIdx.x * 64;
    const float scale = 0.08838834764831845f;  // 1/sqrt(128)

    #pragma unroll
    for (int it = 0; it < 4; it++) {
        int idx = it * 256 + tid;
        int r = idx >> 4, c = (idx & 15) * 8;
        *(uint4*)&Qs[r * 136 + c] =
            *(const uint4*)(qb + (size_t)(b*NQ + q0 + r) * MD + h*HD + c);
    }
    __syncthreads();
    bf16x8 aq[4];
    #pragma unroll
    for (int dk = 0; dk < 4; dk++)
        aq[dk] = *(const bf16x8*)&Qs[(wave*16 + lr) * 136 + dk*32 + quad*8];

    f32x4 acc[8];
    #pragma unroll
    for (int n = 0; n < 8; n++) acc[n] = (f32x4)0.0f;
    float m_run[4], l_run[4];
    #pragma unroll
    for (int r = 0; r < 4; r++) { m_run[r] = -1e30f; l_run[r] = 0.0f; }

    unsigned short* Pw = &Ps[wave * 16 * 40];
    int nch = causal ? (2 * blockIdx.x + 2) : (NT / 32);

    for (int tc = 0; tc < nch; tc++) {
        int t0 = tc * 32;
        __syncthreads();
        #pragma unroll
        for (int it = 0; it < 2; it++) {
            int idx = it * 256 + tid;
            int r = idx >> 4, c = (idx & 15) * 8;
            *(uint4*)&Ks[r * 136 + c] =
                *(const uint4*)(kb + (size_t)(b*NT + t0 + r) * MD + h*HD + c);
        }
        #pragma unroll
        for (int it = 0; it < 2; it++) {
            int idx = it * 256 + tid;
            int r = idx >> 2, c = (idx & 3) * 8;
            *(uint4*)&Vs[r * 40 + c] =
                *(const uint4*)(vbt + ((size_t)(b*NH + h)*HD + r) * NT + t0 + c);
        }
        __syncthreads();

        f32x4 s0 = (f32x4)0.0f, s1 = (f32x4)0.0f;
        #pragma unroll
        for (int dk = 0; dk < 4; dk++) {
            bf16x8 bk0 = *(const bf16x8*)&Ks[(lr) * 136 + dk*32 + quad*8];
            bf16x8 bk1 = *(const bf16x8*)&Ks[(16 + lr) * 136 + dk*32 + quad*8];
            s0 = __builtin_amdgcn_mfma_f32_16x16x32_bf16(aq[dk], bk0, s0, 0, 0, 0);
            s1 = __builtin_amdgcn_mfma_f32_16x16x32_bf16(aq[dk], bk1, s1, 0, 0, 0);
        }
        int grow_base = q0 + wave*16 + quad*4;
        #pragma unroll
        for (int r = 0; r < 4; r++) {
            float v0 = s0[r] * scale, v1 = s1[r] * scale;
            if (causal) {
                if (t0 + lr > grow_base + r)      v0 = -1e30f;
                if (t0 + 16 + lr > grow_base + r) v1 = -1e30f;
            }
            s0[r] = v0; s1[r] = v1;
        }

        #pragma unroll
        for (int r = 0; r < 4; r++) {
            float mx = fmaxf(s0[r], s1[r]);
            #pragma unroll
            for (int off = 1; off < 16; off <<= 1)
                mx = fmaxf(mx, __shfl_xor(mx, off));
            mx = fmaxf(mx, m_run[r]);
            float alpha = __expf(m_run[r] - mx);
            float p0 = __expf(s0[r] - mx);
            float p1 = __expf(s1[r] - mx);
            Pw[(quad*4 + r) * 40 + lr]      = f2bf(p0);
            Pw[(quad*4 + r) * 40 + 16 + lr] = f2bf(p1);
            float psum = p0 + p1;
            #pragma unroll
            for (int off = 1; off < 16; off <<= 1)
                psum += __shfl_xor(psum, off);
            l_run[r] = l_run[r] * alpha + psum;
            m_run[r] = mx;
            #pragma unroll
            for (int n = 0; n < 8; n++) acc[n][r] *= alpha;
        }

        bf16x8 ap = *(const bf16x8*)&Pw[lr * 40 + quad * 8];
        #pragma unroll
        for (int n = 0; n < 8; n++) {
            bf16x8 bv = *(const bf16x8*)&Vs[(n*16 + lr) * 40 + quad * 8];
            acc[n] = __builtin_amdgcn_mfma_f32_16x16x32_bf16(ap, bv, acc[n], 0, 0, 0);
        }
    }

    float linv[4];
    #pragma unroll
    for (int r = 0; r < 4; r++) linv[r] = 1.0f / l_run[r];
    #pragma unroll
    for (int n = 0; n < 8; n++) {
        int gcol = h*HD + n*16 + lr;
        #pragma unroll
        for (int r = 0; r < 4; r++) {
            int grow = q0 + wave*16 + quad*4 + r;
            pr[(size_t)(b*NQ + grow) * MD + gcol] = f2bf(acc[n][r] * linv[r]);
        }
    }
}

// ---------------------------------------------------------------------------
extern "C" void kernel_launch(void* const* d_in, const int* in_sizes, int n_in,
                              void* d_out, int out_size, void* d_ws, size_t ws_size,
                              hipStream_t stream)
{
    const float* enc  = (const float*)d_in[0];
    const float* x    = (const float*)d_in[1];
    const float* swq  = (const float*)d_in[5];
    const float* swk  = (const float*)d_in[6];
    const float* swv  = (const float*)d_in[7];
    const float* swo  = (const float*)d_in[8];
    const float* cwq  = (const float*)d_in[9];
    const float* cwk  = (const float*)d_in[10];
    const float* cwv  = (const float*)d_in[11];
    const float* cwo  = (const float*)d_in[12];
    const float* w1   = (const float*)d_in[13];
    const float* b1   = (const float*)d_in[14];
    const float* w2   = (const float*)d_in[15];
    const float* b2   = (const float*)d_in[16];
    const float* ln1g = (const float*)d_in[17];
    const float* ln1b = (const float*)d_in[18];
    const float* ln2g = (const float*)d_in[19];
    const float* ln2b = (const float*)d_in[20];
    const float* ln3g = (const float*)d_in[21];
    const float* ln3b = (const float*)d_in[22];

    float* h = (float*)d_out;
    unsigned short* u = (unsigned short*)d_ws;
    const size_t MW = 1024 * 1024;
    unsigned short* nb   = u;             // 4M ushort
    unsigned short* encb = u + 4*MW;      // 4M
    unsigned short* qb   = u + 8*MW;      // 4M
    unsigned short* kb   = u + 12*MW;     // 4M
    unsigned short* vbt  = u + 16*MW;     // 4M
    unsigned short* pr   = u + 20*MW;     // 4M
    unsigned short* sb   = qb;            // aliases qb..pr (16M), FFN-only
    unsigned short* wb   = u + 24*MW;

    bool upfront = ws_size >= (size_t)240 * MW;

    hipMemcpyAsync(h, x, 4*MW*sizeof(float), hipMemcpyDeviceToDevice, stream);

    dim3 tb(256);
    cast_bf16<<<4096, tb, 0, stream>>>(enc, encb);

    if (upfront) {
        transpose_cast<<<dim3(4,32,48),  tb, 0, stream>>>(swq, wb + 0*MW,  1024, 128);
        transpose_cast<<<dim3(4,32,48),  tb, 0, stream>>>(swk, wb + 6*MW,  1024, 128);
        transpose_cast<<<dim3(4,32,48),  tb, 0, stream>>>(swv, wb + 12*MW, 1024, 128);
        transpose_cast<<<dim3(32,32,6),  tb, 0, stream>>>(swo, wb + 18*MW, 1024, 1024);
        transpose_cast<<<dim3(4,32,48),  tb, 0, stream>>>(cwq, wb + 24*MW, 1024, 128);
        transpose_cast<<<dim3(4,32,48),  tb, 0, stream>>>(cwk, wb + 30*MW, 1024, 128);
        transpose_cast<<<dim3(4,32,48),  tb, 0, stream>>>(cwv, wb + 36*MW, 1024, 128);
        transpose_cast<<<dim3(32,32,6),  tb, 0, stream>>>(cwo, wb + 42*MW, 1024, 1024);
        transpose_cast<<<dim3(128,32,6), tb, 0, stream>>>(w1,  wb + 48*MW, 1024, 4096);
        transpose_cast<<<dim3(32,128,6), tb, 0, stream>>>(w2,  wb + 72*MW, 4096, 1024);
    }

    dim3 gQKV(24, 32), gO(8, 32, 2), gF1(32, 32), gF2(8, 32, 4), gA(16, 32);

    for (int l = 0; l < NL; l++) {
        unsigned short *pwq, *pwk, *pwv, *pwo, *pcq, *pck, *pcv, *pco, *pw1, *pw2;
        if (upfront) {
            pwq = wb + 0*MW  + l*MW;  pwk = wb + 6*MW  + l*MW;
            pwv = wb + 12*MW + l*MW;  pwo = wb + 18*MW + l*MW;
            pcq = wb + 24*MW + l*MW;  pck = wb + 30*MW + l*MW;
            pcv = wb + 36*MW + l*MW;  pco = wb + 42*MW + l*MW;
            pw1 = wb + 48*MW + l*4*MW; pw2 = wb + 72*MW + l*4*MW;
        } else {
            pwq = wb;        pwk = wb + 1*MW; pwv = wb + 2*MW; pwo = wb + 3*MW;
            pcq = wb + 4*MW; pck = wb + 5*MW; pcv = wb + 6*MW; pco = wb + 7*MW;
            pw1 = wb + 8*MW; pw2 = wb + 12*MW;
            transpose_cast<<<dim3(4,32,8),   tb, 0, stream>>>(swq + l*MW,   pwq, 1024, 128);
            transpose_cast<<<dim3(4,32,8),   tb, 0, stream>>>(swk + l*MW,   pwk, 1024, 128);
            transpose_cast<<<dim3(4,32,8),   tb, 0, stream>>>(swv + l*MW,   pwv, 1024, 128);
            transpose_cast<<<dim3(32,32,1),  tb, 0, stream>>>(swo + l*MW,   pwo, 1024, 1024);
            transpose_cast<<<dim3(4,32,8),   tb, 0, stream>>>(cwq + l*MW,   pcq, 1024, 128);
            transpose_cast<<<dim3(4,32,8),   tb, 0, stream>>>(cwk + l*MW,   pck, 1024, 128);
            transpose_cast<<<dim3(4,32,8),   tb, 0, stream>>>(cwv + l*MW,   pcv, 1024, 128);
            transpose_cast<<<dim3(32,32,1),  tb, 0, stream>>>(cwo + l*MW,   pco, 1024, 1024);
            transpose_cast<<<dim3(128,32,1), tb, 0, stream>>>(w1 + l*4*MW,  pw1, 1024, 4096);
            transpose_cast<<<dim3(32,128,1), tb, 0, stream>>>(w2 + l*4*MW,  pw2, 4096, 1024);
        }

        // ---- self attention ----
        ln_kernel<<<ROWS, tb, 0, stream>>>(h, nb, ln1g + l*MD, ln1b + l*MD);
        gemm_qkv<<<gQKV, tb, 0, stream>>>(nb, nb, pwq, pwk, pwv, qb, kb, vbt);
        attn_mfma<<<gA, tb, 0, stream>>>(qb, kb, vbt, pr, 1);
        gemm_bf16<<<gO, tb, 0, stream>>>(pr, MD, pwo, MD, h, MD, 512, 2, nullptr);

        // ---- cross attention ----
        ln_kernel<<<ROWS, tb, 0, stream>>>(h, nb, ln2g + l*MD, ln2b + l*MD);
        gemm_qkv<<<gQKV, tb, 0, stream>>>(nb, encb, pcq, pck, pcv, qb, kb, vbt);
        attn_mfma<<<gA, tb, 0, stream>>>(qb, kb, vbt, pr, 0);
        gemm_bf16<<<gO, tb, 0, stream>>>(pr, MD, pco, MD, h, MD, 512, 2, nullptr);

        // ---- FFN ----
        ln_kernel<<<ROWS, tb, 0, stream>>>(h, nb, ln3g + l*MD, ln3b + l*MD);
        gemm_bf16<<<gF1, tb, 0, stream>>>(nb, MD, pw1, MD, sb, FF, 1024, 4 | 8, b1 + l*FF);
        gemm_bf16<<<gF2, tb, 0, stream>>>(sb, FF, pw2, FF, h, MD, 1024, 2 | 4, b2 + l*MD);
    }
}

// Round 4
// 3503.843 us; speedup vs baseline: 5.6319x; 1.0627x over previous
//
#include <hip/hip_runtime.h>
#include <math.h>

// Problem constants (Decoder_88871463288984)
#define NL 6
#define NH 8
#define MD 1024
#define HD 128
#define FF 4096
#define NB 4
#define NQ 1024
#define NT 1024
#define ROWS (NB*NQ)   // 4096

typedef __attribute__((ext_vector_type(8))) short bf16x8;
typedef __attribute__((ext_vector_type(4))) float f32x4;

// fp32 -> bf16, round-to-nearest-even
__device__ __forceinline__ unsigned short f2bf(float f) {
    unsigned int u = __float_as_uint(f);
    u += 0x7fffu + ((u >> 16) & 1u);
    return (unsigned short)(u >> 16);
}

// async global->LDS, 16 bytes per lane (dst must be wave-uniform base + lane*16)
__device__ __forceinline__ void load16_lds(const unsigned short* g, unsigned short* l) {
    __builtin_amdgcn_global_load_lds(
        (const __attribute__((address_space(1))) unsigned int*)g,
        (__attribute__((address_space(3))) unsigned int*)l, 16, 0, 0);
}

// ---------------------------------------------------------------------------
// LayerNorm: fp32 in (h), bf16 out. One block per row of 1024.
// ---------------------------------------------------------------------------
__global__ __launch_bounds__(256) void ln_kernel(
    const float* __restrict__ x, unsigned short* __restrict__ y,
    const float* __restrict__ g, const float* __restrict__ b)
{
    __shared__ float sdata[8];
    int row = blockIdx.x;
    int tid = threadIdx.x;
    const float* xr = x + (size_t)row * MD;
    float4 v = ((const float4*)xr)[tid];
    float s = v.x + v.y + v.z + v.w;
    #pragma unroll
    for (int o = 32; o > 0; o >>= 1) s += __shfl_down(s, o, 64);
    if ((tid & 63) == 0) sdata[tid >> 6] = s;
    __syncthreads();
    if (tid == 0) sdata[4] = sdata[0] + sdata[1] + sdata[2] + sdata[3];
    __syncthreads();
    float mean = sdata[4] * (1.0f / MD);
    float4 d = make_float4(v.x - mean, v.y - mean, v.z - mean, v.w - mean);
    float sq = d.x*d.x + d.y*d.y + d.z*d.z + d.w*d.w;
    #pragma unroll
    for (int o = 32; o > 0; o >>= 1) sq += __shfl_down(sq, o, 64);
    __syncthreads();
    if ((tid & 63) == 0) sdata[tid >> 6] = sq;
    __syncthreads();
    if (tid == 0) sdata[4] = sdata[0] + sdata[1] + sdata[2] + sdata[3];
    __syncthreads();
    float var = sdata[4] * (1.0f / MD);
    float rstd = rsqrtf(var + 1e-5f);
    float4 g4 = ((const float4*)g)[tid];
    float4 b4 = ((const float4*)b)[tid];
    ushort4 o;
    o.x = f2bf(d.x * rstd * g4.x + b4.x);
    o.y = f2bf(d.y * rstd * g4.y + b4.y);
    o.z = f2bf(d.z * rstd * g4.z + b4.z);
    o.w = f2bf(d.w * rstd * g4.w + b4.w);
    *(ushort4*)(y + (size_t)row * MD + tid * 4) = o;
}

// ---------------------------------------------------------------------------
// fp32 -> bf16 cast (enc_out). n = grid*256*4 elements exactly.
// ---------------------------------------------------------------------------
__global__ __launch_bounds__(256) void cast_bf16(
    const float* __restrict__ x, unsigned short* __restrict__ y)
{
    int i = blockIdx.x * 256 + threadIdx.x;
    float4 v = ((const float4*)x)[i];
    ushort4 o;
    o.x = f2bf(v.x); o.y = f2bf(v.y); o.z = f2bf(v.z); o.w = f2bf(v.w);
    ((ushort4*)y)[i] = o;
}

// ---------------------------------------------------------------------------
// Batched transpose + cast: X fp32 (batch,R,C) -> Y bf16 (batch,C,R).
// ---------------------------------------------------------------------------
__global__ __launch_bounds__(256) void transpose_cast(
    const float* __restrict__ X, unsigned short* __restrict__ Y, int R, int C)
{
    __shared__ float tile[32][33];
    int bz = blockIdx.z;
    int r0 = blockIdx.y * 32, c0 = blockIdx.x * 32;
    const float* Xb = X + (size_t)bz * R * C;
    unsigned short* Yb = Y + (size_t)bz * R * C;
    int tx = threadIdx.x & 31, ty = threadIdx.x >> 5;
    #pragma unroll
    for (int i = 0; i < 4; i++)
        tile[ty + i*8][tx] = Xb[(size_t)(r0 + ty + i*8) * C + c0 + tx];
    __syncthreads();
    #pragma unroll
    for (int i = 0; i < 4; i++)
        Yb[(size_t)(c0 + ty + i*8) * R + r0 + tx] = f2bf(tile[tx][ty + i*8]);
}

// ---------------------------------------------------------------------------
// Shared bf16 MFMA GEMM body, DOUBLE-BUFFERED single-barrier K-loop.
// Tile 128x128, BK=64, 4 waves x (4x4) 16x16x32, fp32 accum.
// LDS: As/Bs are 2x 16KB each (64 KB/block -> 2 blocks/CU; the dbuf overlap
// replaces the occupancy we can't have).
// flags: 1 = write V^T layout (b,h,d,t) bf16
//        2 = fp32 atomicAdd into Cout (residual / split-K accumulate)
//        4 = add bias[col]
//        8 = ReLU
// ---------------------------------------------------------------------------
#define BKK 64
#define ASZ (128 * BKK)

__device__ __forceinline__ void stage_tiles(
    unsigned short* As, unsigned short* Bs,
    const unsigned short* __restrict__ A, int lda,
    const unsigned short* __restrict__ BT, int ldb,
    int row0, int col0, int kt)
{
    int tid = threadIdx.x;
    #pragma unroll
    for (int it = 0; it < 4; it++) {
        int idx = it * 256 + tid;
        int r = idx >> 3, c = (idx & 7) * 8;
        load16_lds(A + (size_t)(row0 + r) * lda + kt + c, &As[idx * 8]);
    }
    #pragma unroll
    for (int it = 0; it < 4; it++) {
        int idx = it * 256 + tid;
        int r = idx >> 3, c = (idx & 7) * 8;
        load16_lds(BT + (size_t)(col0 + r) * ldb + kt + c, &Bs[idx * 8]);
    }
}

__device__ __forceinline__ void gemm_body(
    unsigned short* As, unsigned short* Bs,
    const unsigned short* __restrict__ A, int lda,
    const unsigned short* __restrict__ BT, int ldb,
    void* __restrict__ Cout, int ldc, int Kdim, int flags,
    const float* __restrict__ bias, int row0, int col0)
{
    int tid = threadIdx.x;
    int lane = tid & 63;
    int wave = tid >> 6;
    int mr = (wave & 1) * 64;
    int nc = (wave >> 1) * 64;
    int lr = lane & 15;
    int quad = lane >> 4;

    f32x4 acc[4][4];
    #pragma unroll
    for (int i = 0; i < 4; i++)
        #pragma unroll
        for (int j = 0; j < 4; j++) acc[i][j] = (f32x4)0.0f;

    const int NKi = Kdim >> 6;
    // prologue: stage k=0 into buffer 0, wait
    stage_tiles(As, Bs, A, lda, BT, ldb, row0, col0, 0);
    __syncthreads();

    for (int k = 0; k < NKi; k++) {
        unsigned short* cA = As + (k & 1) * ASZ;
        unsigned short* cB = Bs + (k & 1) * ASZ;
        // issue next-tile DMA first; it overlaps this iteration's compute.
        if (k + 1 < NKi)
            stage_tiles(As + ((k + 1) & 1) * ASZ, Bs + ((k + 1) & 1) * ASZ,
                        A, lda, BT, ldb, row0, col0, (k + 1) * BKK);
        #pragma unroll
        for (int ks = 0; ks < 2; ks++) {
            bf16x8 af[4], bfr[4];
            #pragma unroll
            for (int i = 0; i < 4; i++)
                af[i] = *(const bf16x8*)&cA[(mr + i*16 + lr) * BKK + ks*32 + quad*8];
            #pragma unroll
            for (int j = 0; j < 4; j++)
                bfr[j] = *(const bf16x8*)&cB[(nc + j*16 + lr) * BKK + ks*32 + quad*8];
            #pragma unroll
            for (int i = 0; i < 4; i++)
                #pragma unroll
                for (int j = 0; j < 4; j++)
                    acc[i][j] = __builtin_amdgcn_mfma_f32_16x16x32_bf16(
                        af[i], bfr[j], acc[i][j], 0, 0, 0);
        }
        // one barrier per iter: waits compute ds_reads (lgkm) AND the k+1
        // stage DMA (vmcnt) -- which has had the whole compute phase in flight.
        __syncthreads();
    }

    float bvj[4];
    if (flags & 4) {
        #pragma unroll
        for (int j = 0; j < 4; j++) bvj[j] = bias[col0 + nc + j*16 + lr];
    } else {
        #pragma unroll
        for (int j = 0; j < 4; j++) bvj[j] = 0.0f;
    }

    if (flags & 1) {
        // V^T store: vbt[((b*8+h)*128 + d) * NT + t], 4 consecutive t packed
        unsigned short* V = (unsigned short*)Cout;
        #pragma unroll
        for (int i = 0; i < 4; i++) {
            int grow0 = row0 + mr + i*16 + quad*4;
            int bb = grow0 >> 10, tt = grow0 & 1023;
            #pragma unroll
            for (int j = 0; j < 4; j++) {
                int gcol = col0 + nc + j*16 + lr;
                int hh = gcol >> 7, dd = gcol & 127;
                ushort4 pk;
                pk.x = f2bf(acc[i][j][0]); pk.y = f2bf(acc[i][j][1]);
                pk.z = f2bf(acc[i][j][2]); pk.w = f2bf(acc[i][j][3]);
                *(ushort4*)(V + (((size_t)(bb*NH + hh)*HD + dd) * NT + tt)) = pk;
            }
        }
    } else if (flags & 2) {
        float* Cf = (float*)Cout;
        #pragma unroll
        for (int i = 0; i < 4; i++) {
            int grow0 = row0 + mr + i*16 + quad*4;
            #pragma unroll
            for (int j = 0; j < 4; j++) {
                int gcol = col0 + nc + j*16 + lr;
                #pragma unroll
                for (int r = 0; r < 4; r++) {
                    float v = acc[i][j][r] + bvj[j];
                    atomicAdd(&Cf[(size_t)(grow0 + r) * ldc + gcol], v);
                }
            }
        }
    } else {
        unsigned short* Cb = (unsigned short*)Cout;
        #pragma unroll
        for (int i = 0; i < 4; i++) {
            int grow0 = row0 + mr + i*16 + quad*4;
            #pragma unroll
            for (int j = 0; j < 4; j++) {
                int gcol = col0 + nc + j*16 + lr;
                #pragma unroll
                for (int r = 0; r < 4; r++) {
                    float v = acc[i][j][r] + bvj[j];
                    if (flags & 8) v = fmaxf(v, 0.0f);
                    Cb[(size_t)(grow0 + r) * ldc + gcol] = f2bf(v);
                }
            }
        }
    }
}

// Generic GEMM with K-split over blockIdx.z (Kper = K per split).
__global__ __launch_bounds__(256) void gemm_bf16(
    const unsigned short* __restrict__ A, int lda,
    const unsigned short* __restrict__ BT, int ldb,
    void* __restrict__ Cout, int ldc, int Kper, int flags,
    const float* __restrict__ bias)
{
    __shared__ unsigned short As[2 * ASZ];
    __shared__ unsigned short Bs[2 * ASZ];
    int row0 = blockIdx.y * 128, col0 = blockIdx.x * 128;
    int kbase = blockIdx.z * Kper;
    if (blockIdx.z) flags &= ~4;      // bias only once
    gemm_body(As, Bs, A + kbase, lda, BT + kbase, ldb, Cout, ldc,
              Kper, flags, bias, row0, col0);
}

// Fused Q/K/V projection: blockIdx.x in [0,24): weight = x>>3, col = (x&7)*128.
// Q uses Aq, K/V use Akv. V output goes to V^T layout.
__global__ __launch_bounds__(256) void gemm_qkv(
    const unsigned short* __restrict__ Aq,
    const unsigned short* __restrict__ Akv,
    const unsigned short* __restrict__ BTq,
    const unsigned short* __restrict__ BTk,
    const unsigned short* __restrict__ BTv,
    unsigned short* __restrict__ qb,
    unsigned short* __restrict__ kb,
    unsigned short* __restrict__ vbt)
{
    __shared__ unsigned short As[2 * ASZ];
    __shared__ unsigned short Bs[2 * ASZ];
    int w = blockIdx.x >> 3;
    int col0 = (blockIdx.x & 7) * 128;
    int row0 = blockIdx.y * 128;
    const unsigned short* A  = (w == 0) ? Aq : Akv;
    const unsigned short* BT = (w == 0) ? BTq : (w == 1) ? BTk : BTv;
    void* C  = (w == 0) ? (void*)qb : (w == 1) ? (void*)kb : (void*)vbt;
    int flags = (w == 2) ? 1 : 0;
    gemm_body(As, Bs, A, MD, BT, MD, C, MD, MD, flags, nullptr, row0, col0);
}

// ---------------------------------------------------------------------------
// MFMA flash attention (unchanged).
// ---------------------------------------------------------------------------
__global__ __launch_bounds__(256) void attn_mfma(
    const unsigned short* __restrict__ qb, const unsigned short* __restrict__ kb,
    const unsigned short* __restrict__ vbt, unsigned short* __restrict__ pr,
    int causal)
{
    __shared__ unsigned short Qs[64 * 136];
    __shared__ unsigned short Ks[32 * 136];
    __shared__ unsigned short Vs[128 * 40];
    __shared__ unsigned short Ps[4 * 16 * 40];

    int tid = threadIdx.x;
    int lane = tid & 63, wave = tid >> 6;
    int lr = lane & 15, quad = lane >> 4;
    int bh = blockIdx.y;
    int b = bh >> 3, h = bh & 7;
    int q0 = blockIdx.x * 64;
    const float scale = 0.08838834764831845f;  // 1/sqrt(128)

    #pragma unroll
    for (int it = 0; it < 4; it++) {
        int idx = it * 256 + tid;
        int r = idx >> 4, c = (idx & 15) * 8;
        *(uint4*)&Qs[r * 136 + c] =
            *(const uint4*)(qb + (size_t)(b*NQ + q0 + r) * MD + h*HD + c);
    }
    __syncthreads();
    bf16x8 aq[4];
    #pragma unroll
    for (int dk = 0; dk < 4; dk++)
        aq[dk] = *(const bf16x8*)&Qs[(wave*16 + lr) * 136 + dk*32 + quad*8];

    f32x4 acc[8];
    #pragma unroll
    for (int n = 0; n < 8; n++) acc[n] = (f32x4)0.0f;
    float m_run[4], l_run[4];
    #pragma unroll
    for (int r = 0; r < 4; r++) { m_run[r] = -1e30f; l_run[r] = 0.0f; }

    unsigned short* Pw = &Ps[wave * 16 * 40];
    int nch = causal ? (2 * blockIdx.x + 2) : (NT / 32);

    for (int tc = 0; tc < nch; tc++) {
        int t0 = tc * 32;
        __syncthreads();
        #pragma unroll
        for (int it = 0; it < 2; it++) {
            int idx = it * 256 + tid;
            int r = idx >> 4, c = (idx & 15) * 8;
            *(uint4*)&Ks[r * 136 + c] =
                *(const uint4*)(kb + (size_t)(b*NT + t0 + r) * MD + h*HD + c);
        }
        #pragma unroll
        for (int it = 0; it < 2; it++) {
            int idx = it * 256 + tid;
            int r = idx >> 2, c = (idx & 3) * 8;
            *(uint4*)&Vs[r * 40 + c] =
                *(const uint4*)(vbt + ((size_t)(b*NH + h)*HD + r) * NT + t0 + c);
        }
        __syncthreads();

        f32x4 s0 = (f32x4)0.0f, s1 = (f32x4)0.0f;
        #pragma unroll
        for (int dk = 0; dk < 4; dk++) {
            bf16x8 bk0 = *(const bf16x8*)&Ks[(lr) * 136 + dk*32 + quad*8];
            bf16x8 bk1 = *(const bf16x8*)&Ks[(16 + lr) * 136 + dk*32 + quad*8];
            s0 = __builtin_amdgcn_mfma_f32_16x16x32_bf16(aq[dk], bk0, s0, 0, 0, 0);
            s1 = __builtin_amdgcn_mfma_f32_16x16x32_bf16(aq[dk], bk1, s1, 0, 0, 0);
        }
        int grow_base = q0 + wave*16 + quad*4;
        #pragma unroll
        for (int r = 0; r < 4; r++) {
            float v0 = s0[r] * scale, v1 = s1[r] * scale;
            if (causal) {
                if (t0 + lr > grow_base + r)      v0 = -1e30f;
                if (t0 + 16 + lr > grow_base + r) v1 = -1e30f;
            }
            s0[r] = v0; s1[r] = v1;
        }

        #pragma unroll
        for (int r = 0; r < 4; r++) {
            float mx = fmaxf(s0[r], s1[r]);
            #pragma unroll
            for (int off = 1; off < 16; off <<= 1)
                mx = fmaxf(mx, __shfl_xor(mx, off));
            mx = fmaxf(mx, m_run[r]);
            float alpha = __expf(m_run[r] - mx);
            float p0 = __expf(s0[r] - mx);
            float p1 = __expf(s1[r] - mx);
            Pw[(quad*4 + r) * 40 + lr]      = f2bf(p0);
            Pw[(quad*4 + r) * 40 + 16 + lr] = f2bf(p1);
            float psum = p0 + p1;
            #pragma unroll
            for (int off = 1; off < 16; off <<= 1)
                psum += __shfl_xor(psum, off);
            l_run[r] = l_run[r] * alpha + psum;
            m_run[r] = mx;
            #pragma unroll
            for (int n = 0; n < 8; n++) acc[n][r] *= alpha;
        }

        bf16x8 ap = *(const bf16x8*)&Pw[lr * 40 + quad * 8];
        #pragma unroll
        for (int n = 0; n < 8; n++) {
            bf16x8 bv = *(const bf16x8*)&Vs[(n*16 + lr) * 40 + quad * 8];
            acc[n] = __builtin_amdgcn_mfma_f32_16x16x32_bf16(ap, bv, acc[n], 0, 0, 0);
        }
    }

    float linv[4];
    #pragma unroll
    for (int r = 0; r < 4; r++) linv[r] = 1.0f / l_run[r];
    #pragma unroll
    for (int n = 0; n < 8; n++) {
        int gcol = h*HD + n*16 + lr;
        #pragma unroll
        for (int r = 0; r < 4; r++) {
            int grow = q0 + wave*16 + quad*4 + r;
            pr[(size_t)(b*NQ + grow) * MD + gcol] = f2bf(acc[n][r] * linv[r]);
        }
    }
}

// ---------------------------------------------------------------------------
extern "C" void kernel_launch(void* const* d_in, const int* in_sizes, int n_in,
                              void* d_out, int out_size, void* d_ws, size_t ws_size,
                              hipStream_t stream)
{
    const float* enc  = (const float*)d_in[0];
    const float* x    = (const float*)d_in[1];
    const float* swq  = (const float*)d_in[5];
    const float* swk  = (const float*)d_in[6];
    const float* swv  = (const float*)d_in[7];
    const float* swo  = (const float*)d_in[8];
    const float* cwq  = (const float*)d_in[9];
    const float* cwk  = (const float*)d_in[10];
    const float* cwv  = (const float*)d_in[11];
    const float* cwo  = (const float*)d_in[12];
    const float* w1   = (const float*)d_in[13];
    const float* b1   = (const float*)d_in[14];
    const float* w2   = (const float*)d_in[15];
    const float* b2   = (const float*)d_in[16];
    const float* ln1g = (const float*)d_in[17];
    const float* ln1b = (const float*)d_in[18];
    const float* ln2g = (const float*)d_in[19];
    const float* ln2b = (const float*)d_in[20];
    const float* ln3g = (const float*)d_in[21];
    const float* ln3b = (const float*)d_in[22];

    float* h = (float*)d_out;
    unsigned short* u = (unsigned short*)d_ws;
    const size_t MW = 1024 * 1024;
    unsigned short* nb   = u;             // 4M ushort
    unsigned short* encb = u + 4*MW;      // 4M
    unsigned short* qb   = u + 8*MW;      // 4M
    unsigned short* kb   = u + 12*MW;     // 4M
    unsigned short* vbt  = u + 16*MW;     // 4M
    unsigned short* pr   = u + 20*MW;     // 4M
    unsigned short* sb   = qb;            // aliases qb..pr (16M), FFN-only
    unsigned short* wb   = u + 24*MW;

    bool upfront = ws_size >= (size_t)240 * MW;

    hipMemcpyAsync(h, x, 4*MW*sizeof(float), hipMemcpyDeviceToDevice, stream);

    dim3 tb(256);
    cast_bf16<<<4096, tb, 0, stream>>>(enc, encb);

    if (upfront) {
        transpose_cast<<<dim3(4,32,48),  tb, 0, stream>>>(swq, wb + 0*MW,  1024, 128);
        transpose_cast<<<dim3(4,32,48),  tb, 0, stream>>>(swk, wb + 6*MW,  1024, 128);
        transpose_cast<<<dim3(4,32,48),  tb, 0, stream>>>(swv, wb + 12*MW, 1024, 128);
        transpose_cast<<<dim3(32,32,6),  tb, 0, stream>>>(swo, wb + 18*MW, 1024, 1024);
        transpose_cast<<<dim3(4,32,48),  tb, 0, stream>>>(cwq, wb + 24*MW, 1024, 128);
        transpose_cast<<<dim3(4,32,48),  tb, 0, stream>>>(cwk, wb + 30*MW, 1024, 128);
        transpose_cast<<<dim3(4,32,48),  tb, 0, stream>>>(cwv, wb + 36*MW, 1024, 128);
        transpose_cast<<<dim3(32,32,6),  tb, 0, stream>>>(cwo, wb + 42*MW, 1024, 1024);
        transpose_cast<<<dim3(128,32,6), tb, 0, stream>>>(w1,  wb + 48*MW, 1024, 4096);
        transpose_cast<<<dim3(32,128,6), tb, 0, stream>>>(w2,  wb + 72*MW, 4096, 1024);
    }

    dim3 gQKV(24, 32), gO(8, 32, 2), gF1(32, 32), gF2(8, 32, 2), gA(16, 32);

    for (int l = 0; l < NL; l++) {
        unsigned short *pwq, *pwk, *pwv, *pwo, *pcq, *pck, *pcv, *pco, *pw1, *pw2;
        if (upfront) {
            pwq = wb + 0*MW  + l*MW;  pwk = wb + 6*MW  + l*MW;
            pwv = wb + 12*MW + l*MW;  pwo = wb + 18*MW + l*MW;
            pcq = wb + 24*MW + l*MW;  pck = wb + 30*MW + l*MW;
            pcv = wb + 36*MW + l*MW;  pco = wb + 42*MW + l*MW;
            pw1 = wb + 48*MW + l*4*MW; pw2 = wb + 72*MW + l*4*MW;
        } else {
            pwq = wb;        pwk = wb + 1*MW; pwv = wb + 2*MW; pwo = wb + 3*MW;
            pcq = wb + 4*MW; pck = wb + 5*MW; pcv = wb + 6*MW; pco = wb + 7*MW;
            pw1 = wb + 8*MW; pw2 = wb + 12*MW;
            transpose_cast<<<dim3(4,32,8),   tb, 0, stream>>>(swq + l*MW,   pwq, 1024, 128);
            transpose_cast<<<dim3(4,32,8),   tb, 0, stream>>>(swk + l*MW,   pwk, 1024, 128);
            transpose_cast<<<dim3(4,32,8),   tb, 0, stream>>>(swv + l*MW,   pwv, 1024, 128);
            transpose_cast<<<dim3(32,32,1),  tb, 0, stream>>>(swo + l*MW,   pwo, 1024, 1024);
            transpose_cast<<<dim3(4,32,8),   tb, 0, stream>>>(cwq + l*MW,   pcq, 1024, 128);
            transpose_cast<<<dim3(4,32,8),   tb, 0, stream>>>(cwk + l*MW,   pck, 1024, 128);
            transpose_cast<<<dim3(4,32,8),   tb, 0, stream>>>(cwv + l*MW,   pcv, 1024, 128);
            transpose_cast<<<dim3(32,32,1),  tb, 0, stream>>>(cwo + l*MW,   pco, 1024, 1024);
            transpose_cast<<<dim3(128,32,1), tb, 0, stream>>>(w1 + l*4*MW,  pw1, 1024, 4096);
            transpose_cast<<<dim3(32,128,1), tb, 0, stream>>>(w2 + l*4*MW,  pw2, 4096, 1024);
        }

        // ---- self attention ----
        ln_kernel<<<ROWS, tb, 0, stream>>>(h, nb, ln1g + l*MD, ln1b + l*MD);
        gemm_qkv<<<gQKV, tb, 0, stream>>>(nb, nb, pwq, pwk, pwv, qb, kb, vbt);
        attn_mfma<<<gA, tb, 0, stream>>>(qb, kb, vbt, pr, 1);
        gemm_bf16<<<gO, tb, 0, stream>>>(pr, MD, pwo, MD, h, MD, 512, 2, nullptr);

        // ---- cross attention ----
        ln_kernel<<<ROWS, tb, 0, stream>>>(h, nb, ln2g + l*MD, ln2b + l*MD);
        gemm_qkv<<<gQKV, tb, 0, stream>>>(nb, encb, pcq, pck, pcv, qb, kb, vbt);
        attn_mfma<<<gA, tb, 0, stream>>>(qb, kb, vbt, pr, 0);
        gemm_bf16<<<gO, tb, 0, stream>>>(pr, MD, pco, MD, h, MD, 512, 2, nullptr);

        // ---- FFN ----
        ln_kernel<<<ROWS, tb, 0, stream>>>(h, nb, ln3g + l*MD, ln3b + l*MD);
        gemm_bf16<<<gF1, tb, 0, stream>>>(nb, MD, pw1, MD, sb, FF, 1024, 4 | 8, b1 + l*FF);
        gemm_bf16<<<gF2, tb, 0, stream>>>(sb, FF, pw2, FF, h, MD, 2048, 2 | 4, b2 + l*MD);
    }
}